// Round 8
// baseline (82.398 us; speedup 1.0000x reference)
//
#include <hip/hip_runtime.h>

#define SEQ   512
#define BATCH 256

// Uniform-index lane broadcast via v_readlane.
__device__ __forceinline__ float bcast_f(float v, int srcLane) {
    return __int_as_float(__builtin_amdgcn_readlane(__float_as_int(v), srcLane));
}
// gfx950: v_log_f32 is log2, v_exp_f32 is exp2.
__device__ __forceinline__ float flog2(float x) { return __builtin_amdgcn_logf(x); }
__device__ __forceinline__ float fexp2(float x) { return __builtin_amdgcn_exp2f(x); }
// Barrier draining only LDS ops (lgkmcnt), not vmcnt.
__device__ __forceinline__ void lds_barrier() {
    __asm__ __volatile__("s_waitcnt lgkmcnt(0)\ns_barrier" ::: "memory");
}

// One block (512 threads = 8 waves) per batch column.
// Wave 0 owns the serial diagonal. Per phase J:
//   phase A (parallel): wave0 precomputes diag-block logs -> P[64],Q[64] regs
//                       (P=-a*L, Q=-c*L); helper waves {1,2,3,5,6,7} apply
//                       column block J-1 to row block J (panel) via
//                       ds_add_f32 into part_lds[J]. wid4 idles (it shares
//                       SIMD0 with wave0 -- keep SIMD0's trans pipe clean).
//   B1; wave0: acc = part_lds[J][lane]; pure chain
//         em = readlane(acc, jl); acc += exp2(fma(Q[jl], em, P[jl]))
//       helpers: deep (col J-1 -> row blocks J+1..7, ds_add_f32).
//   B2: expm block J published.
// Maskless diag: lanes i <= jl have L=0 -> P=Q=0 -> term=1.0 exactly; carry
// readlane at step jl precedes lane jl's first contamination; subtract
// (64-lane) once at publish.
__global__ void __launch_bounds__(512, 1)
act_r_kernel(const float* __restrict__ sp, const float* __restrict__ w,
             float* __restrict__ out) {
    __shared__ float x_lds[SEQ];
    __shared__ float expm_lds[SEQ];
    __shared__ float part_lds[8][64];   // [row block][lane], atomically merged

    const int b    = blockIdx.x;
    const int tid  = threadIdx.x;
    const int wid  = __builtin_amdgcn_readfirstlane(tid) >> 6;  // uniform SGPR
    const int lane = tid & 63;

    const float a   = w[0];
    const float c   = w[1];
    const float s   = w[2];
    const float tau = w[3];
    const float h   = w[4];
    const float scale = 86400.0f * h;

    // Helper column split over waves {1,2,3,5,6,7}: 11,11,11,11,10,10.
    int start = 0, cnt = 0;
    if (wid != 0 && wid != 4) {
        const int slot = (wid < 4) ? (wid - 1) : (wid - 2);   // 0..5
        start = (slot <= 4) ? slot * 11 : 54;
        cnt   = (slot < 4) ? 11 : 10;
    }

    ((float*)part_lds)[tid & 511] = 0.0f;   // 8*64 == blockDim
    x_lds[tid] = sp[tid * BATCH + b] * scale;
    lds_barrier();

    float P[64], Q[64];   // wave0 only (dead for helpers)

    for (int J = 0; J < 8; ++J) {
        float evec = 0.0f, xjvec = 0.0f;
        if (J > 0 && cnt > 0) {
            evec  = expm_lds[((J - 1) << 6) | lane];
            xjvec = x_lds[((J - 1) << 6) | lane];
        }

        if (wid == 0) {
            // ---- phase A: precompute diag-block logs (off the chain)
            const float xd = x_lds[(J << 6) | lane];
#pragma unroll
            for (int jl = 0; jl < 64; ++jl) {
                const float L = flog2(fmaxf(xd - bcast_f(xd, jl), 1.0f));
                P[jl] = -a * L;
                Q[jl] = -c * L;
            }
        } else if (cnt > 0 && J > 0) {
            // ---- panel: col block J-1 -> row block J
            const float xr = x_lds[(J << 6) | lane];
            float pacc = 0.0f;
#pragma unroll
            for (int k = 0; k < 11; ++k) {
                const int jc = start + k;
                const float em = bcast_f(evec, jc);
                const float xj = bcast_f(xjvec, jc);
                const float L  = flog2(fmaxf(xr - xj, 1.0f));
                const float t  = fexp2(-fmaf(c, em, a) * L);
                pacc += (k < cnt) ? t : 0.0f;
            }
            atomicAdd(&part_lds[J][lane], pacc);
        }
        lds_barrier();  // B1: panel merged, P/Q ready

        if (wid == 0) {
            float acc = part_lds[J][lane];   // single merged read
            // ---- pure serial chain: readlane -> fma -> exp2 -> add
#pragma unroll
            for (int jl = 0; jl < 64; ++jl) {
                const float em = bcast_f(acc, jl);
                acc += fexp2(fmaf(Q[jl], em, P[jl]));
            }
            expm_lds[(J << 6) | lane] = acc - (float)(64 - lane);  // publish
        } else if (cnt > 0 && J > 0 && J < 7) {
            // ---- deep: col block J-1 -> row blocks J+1..7 (overlaps chain)
            for (int R = J + 1; R < 8; ++R) {
                const float xr = x_lds[(R << 6) | lane];
                float pacc = 0.0f;
#pragma unroll
                for (int k = 0; k < 11; ++k) {
                    const int jc = start + k;
                    const float em = bcast_f(evec, jc);
                    const float xj = bcast_f(xjvec, jc);
                    const float L  = flog2(fmaxf(xr - xj, 1.0f));
                    const float t  = fexp2(-fmaf(c, em, a) * L);
                    pacc += (k < cnt) ? t : 0.0f;
                }
                atomicAdd(&part_lds[R][lane], pacc);
            }
        }
        lds_barrier();  // B2: expm block J published
    }

    // ---- epilogue: all 512 threads, one output each (i = tid, skip 0)
    if (tid >= 1) {
        const float inv_ln2 = 1.4426950408889634f;
        const float q = tau / s * inv_ln2 - flog2(expm_lds[tid]) / s;
        out[(tid - 1) * BATCH + b] = 1.0f / (1.0f + fexp2(q));
    }
}

extern "C" void kernel_launch(void* const* d_in, const int* in_sizes, int n_in,
                              void* d_out, int out_size, void* d_ws, size_t ws_size,
                              hipStream_t stream) {
    const float* sp = (const float*)d_in[0];  // [512, 256, 1] f32
    const float* w  = (const float*)d_in[1];  // [5] f32
    float* out = (float*)d_out;               // [511, 256, 1] f32
    (void)in_sizes; (void)n_in; (void)out_size; (void)d_ws; (void)ws_size;

    act_r_kernel<<<dim3(BATCH), dim3(512), 0, stream>>>(sp, w, out);
}